// Round 9
// baseline (175.044 us; speedup 1.0000x reference)
//
#include <hip/hip_runtime.h>
#include <math.h>

// ws layout (floats)
#define WS_WEFF 0        // 45 cfgs * 225 taps = 10125
#define WS_M    10240    // 4 * 961 = 3844
#define WS_OFF  14336    // off0[4], off1[4]

// ---------------------------------------------------------------------------
// Kernel A (16 blocks x 256): routing + 4-parity MLP via wave reductions;
// weL/wcL/T recomputed per block (cheap); 45 clipped composed kernels and M
// partitioned across blocks.  (Verified rounds 2/5/8.)
// ---------------------------------------------------------------------------
__global__ void prep_kernel(
    const float* __restrict__ WE,  const float* __restrict__ WC,
    const float* __restrict__ W2,
    const float* __restrict__ bw1, const float* __restrict__ bb1,
    const float* __restrict__ bw2, const float* __restrict__ bb2,
    const float* __restrict__ r2w, const float* __restrict__ r2b,
    const float* __restrict__ ow,  const float* __restrict__ ob,
    const float* __restrict__ l1w, const float* __restrict__ l1b,
    const float* __restrict__ l2w, const float* __restrict__ l2b,
    float* __restrict__ ws)
{
    __shared__ float weL[1440], wcL[1440], TL[2025];
    __shared__ float e1L[4][64];
    __shared__ float r2cL[16], rsumS[4], logitsL[2][4];
    const int tid  = threadIdx.x;
    const int bid  = blockIdx.x;
    const int lane = tid & 63, wid = tid >> 6;

    if (wid < 2) {
        float chv = wid ? 0.25f : -0.25f;
        int o = lane;
        float h = fmaxf(0.5f*l1w[2*o] + chv*l1w[2*o+1] + l1b[o], 0.f);
        float a0 = h*l2w[o], a1 = h*l2w[64+o], a2 = h*l2w[128+o], a3 = h*l2w[192+o];
        for (int off = 32; off; off >>= 1) {
            a0 += __shfl_down(a0, off); a1 += __shfl_down(a1, off);
            a2 += __shfl_down(a2, off); a3 += __shfl_down(a3, off);
        }
        if (lane == 0) {
            logitsL[wid][0] = a0 + l2b[0]; logitsL[wid][1] = a1 + l2b[1];
            logitsL[wid][2] = a2 + l2b[2]; logitsL[wid][3] = a3 + l2b[3];
        }
    }
    {
        float chv = (wid & 2) ? 0.25f : -0.25f;   // y parity
        float cwv = (wid & 1) ? 0.25f : -0.25f;   // x parity
        int o = lane;
        e1L[wid][o] = fmaxf(0.5f*bw1[3*o] + chv*bw1[3*o+1] + cwv*bw1[3*o+2] + bb1[o], 0.f);
    }
    __syncthreads();

    if (tid == 0) {
        float rs[4] = {0.f,0.f,0.f,0.f};
        for (int r = 0; r < 2; ++r) {
            float l0=logitsL[r][0], l1v=logitsL[r][1], l2v=logitsL[r][2], l3=logitsL[r][3];
            float mx = fmaxf(fmaxf(l0,l1v), fmaxf(l2v,l3));
            float e0=expf(l0-mx), e1=expf(l1v-mx), e2=expf(l2v-mx), e3=expf(l3-mx);
            float s = e0+e1+e2+e3;
            rs[0]+=e0/s; rs[1]+=e1/s; rs[2]+=e2/s; rs[3]+=e3/s;
        }
        rsumS[0]=rs[0]; rsumS[1]=rs[1]; rsumS[2]=rs[2]; rsumS[3]=rs[3];
    }
    {
        int o = lane;
        float acc = bb2[o];
        #pragma unroll 8
        for (int i = 0; i < 64; ++i) acc += e1L[wid][i]*bw2[o*64+i];
        float e2v = fmaxf(acc, 0.f);
        float v0 = e2v*ow[o],       v1 = e2v*ow[64+o];
        float r0 = e2v*r2w[o],      r1 = e2v*r2w[64+o];
        float r2v= e2v*r2w[128+o],  r3 = e2v*r2w[192+o];
        for (int off = 32; off; off >>= 1) {
            v0 += __shfl_down(v0, off);  v1 += __shfl_down(v1, off);
            r0 += __shfl_down(r0, off);  r1 += __shfl_down(r1, off);
            r2v+= __shfl_down(r2v, off); r3 += __shfl_down(r3, off);
        }
        if (lane == 0) {
            if (bid == 0) { ws[WS_OFF + wid] = v0 + ob[0]; ws[WS_OFF + 4 + wid] = v1 + ob[1]; }
            r2cL[wid*4+0] = 1.f/(1.f+expf(-(r0 + r2b[0])));
            r2cL[wid*4+1] = 1.f/(1.f+expf(-(r1 + r2b[1])));
            r2cL[wid*4+2] = 1.f/(1.f+expf(-(r2v+ r2b[2])));
            r2cL[wid*4+3] = 1.f/(1.f+expf(-(r3 + r2b[3])));
        }
    }
    __syncthreads();

    {
        float rs0=rsumS[0], rs1=rsumS[1], rs2=rsumS[2], rs3=rsumS[3];
        for (int idx = tid; idx < 1440; idx += 256) {
            weL[idx] = rs0*WE[idx] + rs1*WE[1440+idx] + rs2*WE[2880+idx] + rs3*WE[4320+idx];
            wcL[idx] = rs0*WC[idx] + rs1*WC[1440+idx] + rs2*WC[2880+idx] + rs3*WC[4320+idx];
        }
    }
    __syncthreads();

    for (int idx = tid; idx < 2025; idx += 256) {
        int s = idx / 45, t = idx % 45;
        float acc = 0.f;
        #pragma unroll 8
        for (int k = 0; k < 32; ++k) acc += wcL[k*45+s] * weL[k*45+t];
        TL[idx] = acc;
    }
    __syncthreads();

    {
        const int c0 = bid*633, c1 = (c0+633 < 10125) ? c0+633 : 10125;
        for (int idx = c0 + tid; idx < c1; idx += 256) {
            int cfg = idx / 225, u = idx % 225;
            int a = cfg/9, b = (cfg%9)/3, c = cfg%3;
            int ud = u/25, uy = (u%25)/5, ux = u%5;
            int sdlo = (a==0)?2:((a==1)?1:0);
            int sdhi = (a==4)?2:((a==3)?3:4);
            int sylo = (b==0)?1:0, syhi = (b==2)?1:2;
            int sxlo = (c==0)?1:0, sxhi = (c==2)?1:2;
            if (sdlo < ud-4) sdlo = ud-4;
            if (sdhi > ud)   sdhi = ud;
            if (sylo < uy-2) sylo = uy-2;
            if (syhi > uy)   syhi = uy;
            if (sxlo < ux-2) sxlo = ux-2;
            if (sxhi > ux)   sxhi = ux;
            float acc = 0.f;
            for (int sd = sdlo; sd <= sdhi; ++sd)
                for (int sy = sylo; sy <= syhi; ++sy)
                    for (int sx = sxlo; sx <= sxhi; ++sx)
                        acc += TL[(sd*9+sy*3+sx)*45 + (ud-sd)*9 + (uy-sy)*3 + (ux-sx)];
            ws[WS_WEFF + idx] = acc;
        }
    }

    {
        const int c0 = bid*241, c1 = (c0+241 < 3844) ? c0+241 : 3844;
        for (int idx = c0 + tid; idx < c1; idx += 256) {
            int cls = idx / 961, ij = idx % 961;
            float acc = 0.f;
            #pragma unroll
            for (int e = 0; e < 4; ++e) acc += r2cL[cls*4+e]*W2[e*961+ij];
            ws[WS_M + idx] = acc;
        }
    }
}

// ---------------------------------------------------------------------------
// Conv over one depth-half, all 25 taps.  SUB=0: douts 0..15 (cols di 0..19);
// SUB=1: douts 16..30 (cols di 12..30).  INTER => wave-uniform weight indices
// => scalar s_load path.  fs layout: fsA[d*252 + yy*21 + xx].
// ---------------------------------------------------------------------------
template<int SUB, bool INTER>
__device__ __forceinline__ void conv_half(const float* __restrict__ fsA,
                                          const float* __restrict__ wg,
                                          int bc, int ly, int lx, float* o2)
{
    #pragma unroll 1
    for (int t = 0; t < 25; ++t) {
        const int uy = t / 5, ux = t - uy*5;
        const float* f0 = fsA + (ly+uy)*21 + (lx+ux);
        float w[3][9];
        #pragma unroll
        for (int a3 = 0; a3 < 3; ++a3) {
            const int a = SUB ? (a3 + 2) : a3;
            const int cfg = INTER ? (a*9 + 4) : (a*9 + bc);
            #pragma unroll
            for (int ud = 0; ud < 9; ++ud) w[a3][ud] = wg[cfg*225 + ud*25 + t];
        }
        if (SUB == 0) {
            float col[24];
            col[0]=0.f; col[1]=0.f; col[2]=0.f; col[3]=0.f;
            #pragma unroll
            for (int k = 0; k < 20; ++k) col[4+k] = f0[k*252];
            #pragma unroll
            for (int ud = 0; ud < 9; ++ud) {
                o2[0] += w[0][ud] * col[ud];
                o2[1] += w[1][ud] * col[1+ud];
            }
            #pragma unroll
            for (int d = 2; d < 16; ++d) {
                #pragma unroll
                for (int ud = 0; ud < 9; ++ud)
                    o2[d] += w[2][ud] * col[d+ud];
            }
        } else {
            float col[23];
            #pragma unroll
            for (int k = 0; k < 19; ++k) col[k] = f0[(12+k)*252];
            col[19]=0.f; col[20]=0.f; col[21]=0.f; col[22]=0.f;
            #pragma unroll
            for (int dd = 0; dd < 13; ++dd) {           // douts 16..28, a=2
                #pragma unroll
                for (int ud = 0; ud < 9; ++ud)
                    o2[dd] += w[0][ud] * col[dd+ud];
            }
            #pragma unroll
            for (int ud = 0; ud < 9; ++ud) {
                o2[13] += w[1][ud] * col[13+ud];        // dout 29, a=3
                o2[14] += w[2][ud] * col[14+ud];        // dout 30, a=4
            }
        }
    }
}

__device__ __forceinline__ void mix_rows(const float* __restrict__ M,
                                         const float* __restrict__ fcm,
                                         const float* __restrict__ o2f,
                                         float* __restrict__ out,
                                         int gy, int gx, int i0, int ni)
{
    #pragma unroll 1
    for (int k = 0; k < ni; ++k) {
        const int i = i0 + k;
        float acc = fcm[i*252];
        #pragma unroll
        for (int j = 0; j < 31; ++j) acc += M[i*31 + j] * o2f[j];
        out[i*65536 + gy*256 + gx] = acc;
    }
}

// ---------------------------------------------------------------------------
// Kernel B: 512 blocks (16x8 tile), 256 threads = 128 pixels x 2 depth-halves.
// Lanes parity-grouped: cy wave-uniform, cx = half-wave => M rows via s_load.
// o2 in registers; tiny stride-33 LDS exchange; no partial-combine traffic.
// ---------------------------------------------------------------------------
__global__ __launch_bounds__(256, 2)
void conv_kernel(const float* __restrict__ x, const float* __restrict__ ws,
                 float* __restrict__ out)
{
    __shared__ float fsA[7812];   // fs[31][12][21], 31.2 KB
    __shared__ float o2x[4224];   // [128][33], 16.9 KB (stride 33: conflict-free)
    const int tid = threadIdx.x;
    const int x0 = blockIdx.x * 16;
    const int y0 = blockIdx.y * 8;

    float off0[4], off1[4];
    #pragma unroll
    for (int c = 0; c < 4; ++c) { off0[c] = ws[WS_OFF+c]; off1[c] = ws[WS_OFF+4+c]; }

    // ---- bilinear fill of the fea tile (31 x 12 x 20 used, stride 21) ----
    for (int idx = tid; idx < 7440; idx += 256) {
        int c  = idx / 240;
        int r  = idx % 240;
        int yy = r / 20, xx = r % 20;
        int gy = y0 + yy - 2, gx = x0 + xx - 2;
        float v = 0.f;
        if (gy >= 0 && gy < 256 && gx >= 0 && gx < 256) {
            int cls = ((gy & 1) << 1) | (gx & 1);
            float ix = (gx + 0.5f)*0.5f - 0.5f + off0[cls];
            float iy = (gy + 0.5f)*0.5f - 0.5f + off1[cls];
            float xf = floorf(ix), yf = floorf(iy);
            float wx = ix - xf, wy = iy - yf;
            int xi = (int)xf, yi = (int)yf;
            const float* xc = x + c*16384;
            float acc = 0.f;
            if (yi   >= 0 && yi   < 128 && xi   >= 0 && xi   < 128) acc += xc[yi*128+xi]       * (1.f-wy)*(1.f-wx);
            if (yi   >= 0 && yi   < 128 && xi+1 >= 0 && xi+1 < 128) acc += xc[yi*128+xi+1]     * (1.f-wy)*wx;
            if (yi+1 >= 0 && yi+1 < 128 && xi   >= 0 && xi   < 128) acc += xc[(yi+1)*128+xi]   * wy*(1.f-wx);
            if (yi+1 >= 0 && yi+1 < 128 && xi+1 >= 0 && xi+1 < 128) acc += xc[(yi+1)*128+xi+1] * wy*wx;
            v = acc;
        }
        fsA[c*252 + yy*21 + xx] = v;
    }
    __syncthreads();

    // lane mapping: sub = depth half; cy uniform per wave, cx = half-wave
    const int sub = tid >> 7, px = tid & 127;
    const int qx = px & 7, qy = (px >> 3) & 3;
    const int cx = (px >> 5) & 1, cy = (px >> 6) & 1;
    const int lx = qx*2 + cx, ly = qy*2 + cy;
    const int gx = x0 + lx, gy = y0 + ly;
    const int bcls = (gy == 0) ? 0 : ((gy == 255) ? 2 : 1);
    const int ccls = (gx == 0) ? 0 : ((gx == 255) ? 2 : 1);
    const int bc = bcls*3 + ccls;
    const float* wg = ws + WS_WEFF;
    const float* fc = fsA + (ly+2)*21 + (lx+2);
    const bool inter = (x0 != 0) & (x0 != 240) & (y0 != 0) & (y0 != 248);

    float o2[16];
    if (sub == 0) {
        #pragma unroll
        for (int d = 0; d < 16; ++d) o2[d] = fc[d*252];        // conv2 residual (+fea)
        if (inter) conv_half<0,true >(fsA, wg, bc, ly, lx, o2);
        else       conv_half<0,false>(fsA, wg, bc, ly, lx, o2);
        #pragma unroll
        for (int d = 0; d < 16; ++d) o2x[px*33 + d] = o2[d];
    } else {
        #pragma unroll
        for (int k = 0; k < 15; ++k) o2[k] = fc[(16+k)*252];
        o2[15] = 0.f;
        if (inter) conv_half<1,true >(fsA, wg, bc, ly, lx, o2);
        else       conv_half<1,false>(fsA, wg, bc, ly, lx, o2);
        #pragma unroll
        for (int k = 0; k < 15; ++k) o2x[px*33 + 16 + k] = o2[k];
    }
    __syncthreads();

    float o2f[31];
    #pragma unroll
    for (int j = 0; j < 31; ++j) o2f[j] = o2x[px*33 + j];

    // ---- mix: out[i] = fea0[i] + sum_j M[cls][i][j]*o2f[j], rows 16/15 ----
    const int cyu = __builtin_amdgcn_readfirstlane(cy);
    const float* M0 = ws + WS_M + cyu*2*961;
    const int i0 = sub ? 16 : 0, ni = sub ? 15 : 16;
    if (cx == 0) mix_rows(M0,       fc - (ly+2)*21 - (lx+2) + (ly+2)*21 + (lx+2), o2f, out, gy, gx, i0, ni);
    else         mix_rows(M0 + 961, fc, o2f, out, gy, gx, i0, ni);
}

extern "C" void kernel_launch(void* const* d_in, const int* in_sizes, int n_in,
                              void* d_out, int out_size, void* d_ws, size_t ws_size,
                              hipStream_t stream)
{
    const float* x   = (const float*)d_in[0];
    // d_in[1] = scale (int, always 2; shapes are compile-time)
    const float* WE  = (const float*)d_in[2];
    const float* WC  = (const float*)d_in[3];
    const float* W2  = (const float*)d_in[4];
    const float* bw1 = (const float*)d_in[5];
    const float* bb1 = (const float*)d_in[6];
    const float* bw2 = (const float*)d_in[7];
    const float* bb2 = (const float*)d_in[8];
    const float* r2w = (const float*)d_in[9];
    const float* r2b = (const float*)d_in[10];
    const float* ow  = (const float*)d_in[11];
    const float* ob  = (const float*)d_in[12];
    const float* l1w = (const float*)d_in[13];
    const float* l1b = (const float*)d_in[14];
    const float* l2w = (const float*)d_in[15];
    const float* l2b = (const float*)d_in[16];
    float* ws  = (float*)d_ws;
    float* out = (float*)d_out;

    hipLaunchKernelGGL(prep_kernel, dim3(16), dim3(256), 0, stream,
                       WE, WC, W2, bw1, bb1, bw2, bb2, r2w, r2b,
                       ow, ob, l1w, l1b, l2w, l2b, ws);
    hipLaunchKernelGGL(conv_kernel, dim3(16, 32), dim3(256), 0, stream,
                       x, ws, out);
}

// Round 10
// 158.526 us; speedup vs baseline: 1.1042x; 1.1042x over previous
//
#include <hip/hip_runtime.h>
#include <math.h>

// ws layout (floats)
#define WS_WEFF 0        // 45 cfgs * 225 taps = 10125
#define WS_M    10240    // padded [4][31][32] = 3968
#define WS_OFF  14336    // off0[4], off1[4]
#define WS_FEA  16384    // [260][260][36] = 2,433,600 floats
#define FEA_ROW 9360     // 260*36

// ---------------------------------------------------------------------------
// Shared prep body (bid in [0,16)): routing + 4-parity MLP + we/wc/T + weff
// partition + padded-M partition.  (Logic verified rounds 2/5/8/9; M now
// written padded [4][31][32].)
// ---------------------------------------------------------------------------
__device__ __forceinline__ void prep_body(
    int bid, int tid,
    const float* __restrict__ WE,  const float* __restrict__ WC,
    const float* __restrict__ W2,
    const float* __restrict__ bw1, const float* __restrict__ bb1,
    const float* __restrict__ bw2, const float* __restrict__ bb2,
    const float* __restrict__ r2w, const float* __restrict__ r2b,
    const float* __restrict__ ow,  const float* __restrict__ ob,
    const float* __restrict__ l1w, const float* __restrict__ l1b,
    const float* __restrict__ l2w, const float* __restrict__ l2b,
    float* __restrict__ ws,
    float* weL, float* wcL, float* TL, float* e1L, float* r2cL,
    float* rsumS, float* logitsL)
{
    const int lane = tid & 63, wid = tid >> 6;

    if (wid < 2) {
        float chv = wid ? 0.25f : -0.25f;
        int o = lane;
        float h = fmaxf(0.5f*l1w[2*o] + chv*l1w[2*o+1] + l1b[o], 0.f);
        float a0 = h*l2w[o], a1 = h*l2w[64+o], a2 = h*l2w[128+o], a3 = h*l2w[192+o];
        for (int off = 32; off; off >>= 1) {
            a0 += __shfl_down(a0, off); a1 += __shfl_down(a1, off);
            a2 += __shfl_down(a2, off); a3 += __shfl_down(a3, off);
        }
        if (lane == 0) {
            logitsL[wid*4+0] = a0 + l2b[0]; logitsL[wid*4+1] = a1 + l2b[1];
            logitsL[wid*4+2] = a2 + l2b[2]; logitsL[wid*4+3] = a3 + l2b[3];
        }
    }
    {
        float chv = (wid & 2) ? 0.25f : -0.25f;   // y parity
        float cwv = (wid & 1) ? 0.25f : -0.25f;   // x parity
        int o = lane;
        e1L[wid*64+o] = fmaxf(0.5f*bw1[3*o] + chv*bw1[3*o+1] + cwv*bw1[3*o+2] + bb1[o], 0.f);
    }
    __syncthreads();

    if (tid == 0) {
        float rs0=0.f, rs1=0.f, rs2=0.f, rs3=0.f;
        for (int r = 0; r < 2; ++r) {
            float l0=logitsL[r*4+0], l1v=logitsL[r*4+1], l2v=logitsL[r*4+2], l3=logitsL[r*4+3];
            float mx = fmaxf(fmaxf(l0,l1v), fmaxf(l2v,l3));
            float e0=expf(l0-mx), e1=expf(l1v-mx), e2=expf(l2v-mx), e3=expf(l3-mx);
            float s = e0+e1+e2+e3;
            rs0+=e0/s; rs1+=e1/s; rs2+=e2/s; rs3+=e3/s;
        }
        rsumS[0]=rs0; rsumS[1]=rs1; rsumS[2]=rs2; rsumS[3]=rs3;
    }
    {
        int o = lane;
        float acc = bb2[o];
        #pragma unroll 8
        for (int i = 0; i < 64; ++i) acc += e1L[wid*64+i]*bw2[o*64+i];
        float e2v = fmaxf(acc, 0.f);
        float v0 = e2v*ow[o],       v1 = e2v*ow[64+o];
        float r0 = e2v*r2w[o],      r1 = e2v*r2w[64+o];
        float r2v= e2v*r2w[128+o],  r3 = e2v*r2w[192+o];
        for (int off = 32; off; off >>= 1) {
            v0 += __shfl_down(v0, off);  v1 += __shfl_down(v1, off);
            r0 += __shfl_down(r0, off);  r1 += __shfl_down(r1, off);
            r2v+= __shfl_down(r2v, off); r3 += __shfl_down(r3, off);
        }
        if (lane == 0) {
            if (bid == 0) { ws[WS_OFF + wid] = v0 + ob[0]; ws[WS_OFF + 4 + wid] = v1 + ob[1]; }
            r2cL[wid*4+0] = 1.f/(1.f+expf(-(r0 + r2b[0])));
            r2cL[wid*4+1] = 1.f/(1.f+expf(-(r1 + r2b[1])));
            r2cL[wid*4+2] = 1.f/(1.f+expf(-(r2v+ r2b[2])));
            r2cL[wid*4+3] = 1.f/(1.f+expf(-(r3 + r2b[3])));
        }
    }
    __syncthreads();

    {
        float rs0=rsumS[0], rs1=rsumS[1], rs2=rsumS[2], rs3=rsumS[3];
        for (int idx = tid; idx < 1440; idx += 256) {
            weL[idx] = rs0*WE[idx] + rs1*WE[1440+idx] + rs2*WE[2880+idx] + rs3*WE[4320+idx];
            wcL[idx] = rs0*WC[idx] + rs1*WC[1440+idx] + rs2*WC[2880+idx] + rs3*WC[4320+idx];
        }
    }
    __syncthreads();

    for (int idx = tid; idx < 2025; idx += 256) {
        int s = idx / 45, t = idx % 45;
        float acc = 0.f;
        #pragma unroll 8
        for (int k = 0; k < 32; ++k) acc += wcL[k*45+s] * weL[k*45+t];
        TL[idx] = acc;
    }
    __syncthreads();

    {
        const int c0 = bid*633, c1 = (c0+633 < 10125) ? c0+633 : 10125;
        for (int idx = c0 + tid; idx < c1; idx += 256) {
            int cfg = idx / 225, u = idx % 225;
            int a = cfg/9, b = (cfg%9)/3, c = cfg%3;
            int ud = u/25, uy = (u%25)/5, ux = u%5;
            int sdlo = (a==0)?2:((a==1)?1:0);
            int sdhi = (a==4)?2:((a==3)?3:4);
            int sylo = (b==0)?1:0, syhi = (b==2)?1:2;
            int sxlo = (c==0)?1:0, sxhi = (c==2)?1:2;
            if (sdlo < ud-4) sdlo = ud-4;
            if (sdhi > ud)   sdhi = ud;
            if (sylo < uy-2) sylo = uy-2;
            if (syhi > uy)   syhi = uy;
            if (sxlo < ux-2) sxlo = ux-2;
            if (sxhi > ux)   sxhi = ux;
            float acc = 0.f;
            for (int sd = sdlo; sd <= sdhi; ++sd)
                for (int sy = sylo; sy <= syhi; ++sy)
                    for (int sx = sxlo; sx <= sxhi; ++sx)
                        acc += TL[(sd*9+sy*3+sx)*45 + (ud-sd)*9 + (uy-sy)*3 + (ux-sx)];
            ws[WS_WEFF + idx] = acc;
        }
    }

    {   // padded M: [cls][i][32], j==31 -> 0
        const int c0 = bid*248, c1 = c0+248;
        for (int idx = c0 + tid; idx < c1; idx += 256) {
            int cls = idx / 992, r = idx - cls*992;
            int i = r >> 5, j = r & 31;
            float acc = 0.f;
            if (j < 31) {
                #pragma unroll
                for (int e = 0; e < 4; ++e) acc += r2cL[cls*4+e]*W2[e*961 + i*31 + j];
            }
            ws[WS_M + idx] = acc;
        }
    }
}

// ---------------------------------------------------------------------------
// Fill body: one fea position per thread, d-contiguous float4 stores.
// Offsets computed locally (4-wave mini-MLP) to avoid cross-block ordering.
// ---------------------------------------------------------------------------
__device__ __forceinline__ void fill_body(
    int fb, int tid, const float* __restrict__ x,
    const float* __restrict__ bw1, const float* __restrict__ bb1,
    const float* __restrict__ bw2, const float* __restrict__ bb2,
    const float* __restrict__ ow,  const float* __restrict__ ob,
    float* __restrict__ ws, float* e1L, float* offS)
{
    const int lane = tid & 63, wid = tid >> 6;
    {
        float chv = (wid & 2) ? 0.25f : -0.25f;
        float cwv = (wid & 1) ? 0.25f : -0.25f;
        int o = lane;
        e1L[wid*64+o] = fmaxf(0.5f*bw1[3*o] + chv*bw1[3*o+1] + cwv*bw1[3*o+2] + bb1[o], 0.f);
    }
    __syncthreads();
    {
        int o = lane;
        float acc = bb2[o];
        #pragma unroll 8
        for (int i = 0; i < 64; ++i) acc += e1L[wid*64+i]*bw2[o*64+i];
        float e2v = fmaxf(acc, 0.f);
        float v0 = e2v*ow[o], v1 = e2v*ow[64+o];
        for (int off = 32; off; off >>= 1) {
            v0 += __shfl_down(v0, off); v1 += __shfl_down(v1, off);
        }
        if (lane == 0) { offS[wid] = v0 + ob[0]; offS[4+wid] = v1 + ob[1]; }
    }
    __syncthreads();

    const int fpos = fb*256 + tid;
    if (fpos >= 67600) return;
    const int gy2 = fpos / 260, gx2 = fpos - gy2*260;
    const int gy = gy2 - 2, gx = gx2 - 2;
    float* dst = ws + WS_FEA + (size_t)(gy2*260 + gx2)*36;

    if (gy < 0 || gy >= 256 || gx < 0 || gx >= 256) {
        float4 z = make_float4(0.f,0.f,0.f,0.f);
        #pragma unroll
        for (int c4 = 0; c4 < 8; ++c4) *(float4*)(dst + c4*4) = z;
        return;
    }
    const int cls = ((gy & 1) << 1) | (gx & 1);
    float ix = (gx + 0.5f)*0.5f - 0.5f + offS[cls];
    float iy = (gy + 0.5f)*0.5f - 0.5f + offS[4+cls];
    float xf = floorf(ix), yf = floorf(iy);
    float wx = ix - xf, wy = iy - yf;
    int xi = (int)xf, yi = (int)yf;
    const bool vx0 = (xi   >= 0) & (xi   < 128), vx1 = (xi+1 >= 0) & (xi+1 < 128);
    const bool vy0 = (yi   >= 0) & (yi   < 128), vy1 = (yi+1 >= 0) & (yi+1 < 128);
    const float w00 = (1.f-wy)*(1.f-wx) * (float)(vy0 & vx0);
    const float w01 = (1.f-wy)*wx       * (float)(vy0 & vx1);
    const float w10 = wy*(1.f-wx)       * (float)(vy1 & vx0);
    const float w11 = wy*wx             * (float)(vy1 & vx1);
    const int x0i = min(max(xi,   0), 127), x1i = min(max(xi+1, 0), 127);
    const int y0i = min(max(yi,   0), 127), y1i = min(max(yi+1, 0), 127);
    const int i00 = y0i*128 + x0i, i01 = y0i*128 + x1i;
    const int i10 = y1i*128 + x0i, i11 = y1i*128 + x1i;

    #pragma unroll 1
    for (int c4 = 0; c4 < 8; ++c4) {
        float vv[4];
        #pragma unroll
        for (int j = 0; j < 4; ++j) {
            const int c = c4*4 + j;
            float a = 0.f;
            if (c < 31) {
                const float* xc = x + c*16384;
                a = xc[i00]*w00 + xc[i01]*w01 + xc[i10]*w10 + xc[i11]*w11;
            }
            vv[j] = a;
        }
        *(float4*)(dst + c4*4) = make_float4(vv[0], vv[1], vv[2], vv[3]);
    }
}

__global__ __launch_bounds__(256)
void prepfill_kernel(const float* __restrict__ x,
    const float* __restrict__ WE,  const float* __restrict__ WC,
    const float* __restrict__ W2,
    const float* __restrict__ bw1, const float* __restrict__ bb1,
    const float* __restrict__ bw2, const float* __restrict__ bb2,
    const float* __restrict__ r2w, const float* __restrict__ r2b,
    const float* __restrict__ ow,  const float* __restrict__ ob,
    const float* __restrict__ l1w, const float* __restrict__ l1b,
    const float* __restrict__ l2w, const float* __restrict__ l2b,
    float* __restrict__ ws)
{
    __shared__ float weL[1440], wcL[1440], TL[2025], e1L[256];
    __shared__ float r2cL[16], rsumS[4], logitsL[8], offS[8];
    if (blockIdx.x < 16)
        prep_body(blockIdx.x, threadIdx.x, WE,WC,W2,bw1,bb1,bw2,bb2,r2w,r2b,
                  ow,ob,l1w,l1b,l2w,l2b, ws, weL,wcL,TL,e1L,r2cL,rsumS,logitsL);
    else
        fill_body(blockIdx.x-16, threadIdx.x, x, bw1,bb1,bw2,bb2,ow,ob, ws, e1L, offS);
}

__global__ void prep_only_kernel(
    const float* __restrict__ WE,  const float* __restrict__ WC,
    const float* __restrict__ W2,
    const float* __restrict__ bw1, const float* __restrict__ bb1,
    const float* __restrict__ bw2, const float* __restrict__ bb2,
    const float* __restrict__ r2w, const float* __restrict__ r2b,
    const float* __restrict__ ow,  const float* __restrict__ ob,
    const float* __restrict__ l1w, const float* __restrict__ l1b,
    const float* __restrict__ l2w, const float* __restrict__ l2b,
    float* __restrict__ ws)
{
    __shared__ float weL[1440], wcL[1440], TL[2025], e1L[256];
    __shared__ float r2cL[16], rsumS[4], logitsL[8];
    prep_body(blockIdx.x, threadIdx.x, WE,WC,W2,bw1,bb1,bw2,bb2,r2w,r2b,
              ow,ob,l1w,l1b,l2w,l2b, ws, weL,wcL,TL,e1L,r2cL,rsumS,logitsL);
}

// ---------------------------------------------------------------------------
// Conv over one depth-half with float4 LDS cols.  fsT row stride 724.
// ---------------------------------------------------------------------------
template<int SUB, bool INTER>
__device__ __forceinline__ void conv_half4(const float* __restrict__ fsT,
                                           const float* __restrict__ wg,
                                           int bc, int ly, int lx, float* o2)
{
    #pragma unroll 1
    for (int t = 0; t < 25; ++t) {
        const int uy = t / 5, ux = t - uy*5;
        const float* f0 = fsT + (ly+uy)*724 + (lx+ux)*36 + (SUB ? 12 : 0);
        float4 q0 = *(const float4*)(f0);
        float4 q1 = *(const float4*)(f0+4);
        float4 q2 = *(const float4*)(f0+8);
        float4 q3 = *(const float4*)(f0+12);
        float4 q4 = *(const float4*)(f0+16);
        float w[3][9];
        #pragma unroll
        for (int a3 = 0; a3 < 3; ++a3) {
            const int a = SUB ? (a3 + 2) : a3;
            const int cfg = INTER ? (a*9 + 4) : (a*9 + bc);
            #pragma unroll
            for (int ud = 0; ud < 9; ++ud) w[a3][ud] = wg[cfg*225 + ud*25 + t];
        }
        if (SUB == 0) {
            float col[24];
            col[0]=0.f; col[1]=0.f; col[2]=0.f; col[3]=0.f;
            col[4]=q0.x;  col[5]=q0.y;  col[6]=q0.z;  col[7]=q0.w;
            col[8]=q1.x;  col[9]=q1.y;  col[10]=q1.z; col[11]=q1.w;
            col[12]=q2.x; col[13]=q2.y; col[14]=q2.z; col[15]=q2.w;
            col[16]=q3.x; col[17]=q3.y; col[18]=q3.z; col[19]=q3.w;
            col[20]=q4.x; col[21]=q4.y; col[22]=q4.z; col[23]=q4.w;
            #pragma unroll
            for (int ud = 0; ud < 9; ++ud) {
                o2[0] += w[0][ud] * col[ud];
                o2[1] += w[1][ud] * col[1+ud];
            }
            #pragma unroll
            for (int d = 2; d < 16; ++d) {
                #pragma unroll
                for (int ud = 0; ud < 9; ++ud)
                    o2[d] += w[2][ud] * col[d+ud];
            }
        } else {
            float col[23];
            col[0]=q0.x;  col[1]=q0.y;  col[2]=q0.z;  col[3]=q0.w;
            col[4]=q1.x;  col[5]=q1.y;  col[6]=q1.z;  col[7]=q1.w;
            col[8]=q2.x;  col[9]=q2.y;  col[10]=q2.z; col[11]=q2.w;
            col[12]=q3.x; col[13]=q3.y; col[14]=q3.z; col[15]=q3.w;
            col[16]=q4.x; col[17]=q4.y; col[18]=q4.z; col[19]=q4.w;  // c31==0
            col[20]=0.f; col[21]=0.f; col[22]=0.f;
            #pragma unroll
            for (int dd = 0; dd < 13; ++dd) {           // douts 16..28, a=2
                #pragma unroll
                for (int ud = 0; ud < 9; ++ud)
                    o2[dd] += w[0][ud] * col[dd+ud];
            }
            #pragma unroll
            for (int ud = 0; ud < 9; ++ud) {
                o2[13] += w[1][ud] * col[13+ud];        // dout 29, a=3
                o2[14] += w[2][ud] * col[14+ud];        // dout 30, a=4
            }
        }
    }
}

// ---------------------------------------------------------------------------
// Conv kernel (path A): stage fea tile (coalesced float4) + Ms -> conv ->
// o2x exchange -> mix (float4 Ms reads).  512 blocks, 2 thr/pixel.
// ---------------------------------------------------------------------------
__global__ __launch_bounds__(256, 2)
void conv4_kernel(const float* __restrict__ ws, float* __restrict__ out)
{
    __shared__ float fsT[8688];    // [12][724]
    __shared__ float MsL[3968];    // [4][31][32]
    __shared__ float o2x[4224];    // [128][33]
    const int tid = threadIdx.x;
    const int x0 = blockIdx.x * 16;
    const int y0 = blockIdx.y * 8;

    {
        const float* src0 = ws + WS_FEA + (size_t)y0*FEA_ROW + x0*36;
        #pragma unroll 1
        for (int idx = tid; idx < 2160; idx += 256) {
            int row = idx / 180, ch = idx - row*180;
            *(float4*)(fsT + row*724 + ch*4) = *(const float4*)(src0 + row*FEA_ROW + ch*4);
        }
    }
    #pragma unroll 1
    for (int idx = tid; idx < 992; idx += 256)
        *(float4*)(MsL + idx*4) = *(const float4*)(ws + WS_M + idx*4);
    __syncthreads();

    const int sub = tid >> 7, px = tid & 127;
    const int lx = px & 15, ly = px >> 4;
    const int gx = x0 + lx, gy = y0 + ly;
    const int bcls = (gy == 0) ? 0 : ((gy == 255) ? 2 : 1);
    const int ccls = (gx == 0) ? 0 : ((gx == 255) ? 2 : 1);
    const int bc = bcls*3 + ccls;
    const float* wg = ws + WS_WEFF;
    const float* fc = fsT + (ly+2)*724 + (lx+2)*36;
    const bool inter = (x0 != 0) & (x0 != 240) & (y0 != 0) & (y0 != 248);

    float o2[16];
    if (sub == 0) {
        #pragma unroll
        for (int d = 0; d < 16; ++d) o2[d] = fc[d];            // conv2 residual (+fea)
        if (inter) conv_half4<0,true >(fsT, wg, bc, ly, lx, o2);
        else       conv_half4<0,false>(fsT, wg, bc, ly, lx, o2);
        #pragma unroll
        for (int d = 0; d < 16; ++d) o2x[px*33 + d] = o2[d];
    } else {
        #pragma unroll
        for (int k = 0; k < 15; ++k) o2[k] = fc[16+k];
        o2[15] = 0.f;
        if (inter) conv_half4<1,true >(fsT, wg, bc, ly, lx, o2);
        else       conv_half4<1,false>(fsT, wg, bc, ly, lx, o2);
        #pragma unroll
        for (int k = 0; k < 15; ++k) o2x[px*33 + 16 + k] = o2[k];
    }
    __syncthreads();

    float o2f[31];
    #pragma unroll
    for (int j = 0; j < 31; ++j) o2f[j] = o2x[px*33 + j];

    const int cls = ((gy & 1) << 1) | (gx & 1);
    const float* Mb = MsL + cls*992;
    const int i0 = sub ? 16 : 0, ni = sub ? 15 : 16;
    #pragma unroll 1
    for (int k = 0; k < ni; ++k) {
        const int i = i0 + k;
        const float* mr = Mb + i*32;
        float acc = fc[i];
        #pragma unroll
        for (int q = 0; q < 8; ++q) {
            float4 m = *(const float4*)(mr + q*4);
            acc += m.x*o2f[4*q] + m.y*o2f[4*q+1];
            if (4*q+2 < 31) acc += m.z*o2f[4*q+2];
            if (4*q+3 < 31) acc += m.w*o2f[4*q+3];
        }
        out[i*65536 + gy*256 + gx] = acc;
    }
}

// ---------------------------------------------------------------------------
// Fallback conv (path B, ws too small): R9 in-LDS-bilinear version, adapted
// to padded M.  Verified structure.
// ---------------------------------------------------------------------------
template<int SUB, bool INTER>
__device__ __forceinline__ void conv_half_fb(const float* __restrict__ fsA,
                                             const float* __restrict__ wg,
                                             int bc, int ly, int lx, float* o2)
{
    #pragma unroll 1
    for (int t = 0; t < 25; ++t) {
        const int uy = t / 5, ux = t - uy*5;
        const float* f0 = fsA + (ly+uy)*21 + (lx+ux);
        float w[3][9];
        #pragma unroll
        for (int a3 = 0; a3 < 3; ++a3) {
            const int a = SUB ? (a3 + 2) : a3;
            const int cfg = INTER ? (a*9 + 4) : (a*9 + bc);
            #pragma unroll
            for (int ud = 0; ud < 9; ++ud) w[a3][ud] = wg[cfg*225 + ud*25 + t];
        }
        if (SUB == 0) {
            float col[24];
            col[0]=0.f; col[1]=0.f; col[2]=0.f; col[3]=0.f;
            #pragma unroll
            for (int k2 = 0; k2 < 20; ++k2) col[4+k2] = f0[k2*252];
            #pragma unroll
            for (int ud = 0; ud < 9; ++ud) {
                o2[0] += w[0][ud] * col[ud];
                o2[1] += w[1][ud] * col[1+ud];
            }
            #pragma unroll
            for (int d = 2; d < 16; ++d) {
                #pragma unroll
                for (int ud = 0; ud < 9; ++ud)
                    o2[d] += w[2][ud] * col[d+ud];
            }
        } else {
            float col[23];
            #pragma unroll
            for (int k2 = 0; k2 < 19; ++k2) col[k2] = f0[(12+k2)*252];
            col[19]=0.f; col[20]=0.f; col[21]=0.f; col[22]=0.f;
            #pragma unroll
            for (int dd = 0; dd < 13; ++dd) {
                #pragma unroll
                for (int ud = 0; ud < 9; ++ud)
                    o2[dd] += w[0][ud] * col[dd+ud];
            }
            #pragma unroll
            for (int ud = 0; ud < 9; ++ud) {
                o2[13] += w[1][ud] * col[13+ud];
                o2[14] += w[2][ud] * col[14+ud];
            }
        }
    }
}

__global__ __launch_bounds__(256, 2)
void conv_fb_kernel(const float* __restrict__ x, const float* __restrict__ ws,
                    float* __restrict__ out)
{
    __shared__ float fsA[7812];
    __shared__ float o2x[4224];
    const int tid = threadIdx.x;
    const int x0 = blockIdx.x * 16;
    const int y0 = blockIdx.y * 8;

    float off0[4], off1[4];
    #pragma unroll
    for (int c = 0; c < 4; ++c) { off0[c] = ws[WS_OFF+c]; off1[c] = ws[WS_OFF+4+c]; }

    for (int idx = tid; idx < 7440; idx += 256) {
        int c  = idx / 240;
        int r  = idx % 240;
        int yy = r / 20, xx = r % 20;
        int gy = y0 + yy - 2, gx = x0 + xx - 2;
        float v = 0.f;
        if (gy >= 0 && gy < 256 && gx >= 0 && gx < 256) {
            int cls = ((gy & 1) << 1) | (gx & 1);
            float ix = (gx + 0.5f)*0.5f - 0.5f + off0[cls];
            float iy = (gy + 0.5f)*0.5f - 0.5f + off1[cls];
            float xf = floorf(ix), yf = floorf(iy);
            float wx = ix - xf, wy = iy - yf;
            int xi = (int)xf, yi = (int)yf;
            const float* xc = x + c*16384;
            float acc = 0.f;
            if (yi   >= 0 && yi   < 128 && xi   >= 0 && xi   < 128) acc += xc[yi*128+xi]       * (1.f-wy)*(1.f-wx);
            if (yi   >= 0 && yi   < 128 && xi+1 >= 0 && xi+1 < 128) acc += xc[yi*128+xi+1]     * (1.f-wy)*wx;
            if (yi+1 >= 0 && yi+1 < 128 && xi   >= 0 && xi   < 128) acc += xc[(yi+1)*128+xi]   * wy*(1.f-wx);
            if (yi+1 >= 0 && yi+1 < 128 && xi+1 >= 0 && xi+1 < 128) acc += xc[(yi+1)*128+xi+1] * wy*wx;
            v = acc;
        }
        fsA[c*252 + yy*21 + xx] = v;
    }
    __syncthreads();

    const int sub = tid >> 7, px = tid & 127;
    const int lx = px & 15, ly = px >> 4;
    const int gx = x0 + lx, gy = y0 + ly;
    const int bcls = (gy == 0) ? 0 : ((gy == 255) ? 2 : 1);
    const int ccls = (gx == 0) ? 0 : ((gx == 255) ? 2 : 1);
    const int bc = bcls*3 + ccls;
    const float* wg = ws + WS_WEFF;
    const float* fc = fsA + (ly+2)*21 + (lx+2);
    const bool inter = (x0 != 0) & (x0 != 240) & (y0 != 0) & (y0 != 248);

    float o2[16];
    if (sub == 0) {
        #pragma unroll
        for (int d = 0; d < 16; ++d) o2[d] = fc[d*252];
        if (inter) conv_half_fb<0,true >(fsA, wg, bc, ly, lx, o2);
        else       conv_half_fb<0,false>(fsA, wg, bc, ly, lx, o2);
        #pragma unroll
        for (int d = 0; d < 16; ++d) o2x[px*33 + d] = o2[d];
    } else {
        #pragma unroll
        for (int k = 0; k < 15; ++k) o2[k] = fc[(16+k)*252];
        o2[15] = 0.f;
        if (inter) conv_half_fb<1,true >(fsA, wg, bc, ly, lx, o2);
        else       conv_half_fb<1,false>(fsA, wg, bc, ly, lx, o2);
        #pragma unroll
        for (int k = 0; k < 15; ++k) o2x[px*33 + 16 + k] = o2[k];
    }
    __syncthreads();

    float o2f[31];
    #pragma unroll
    for (int j = 0; j < 31; ++j) o2f[j] = o2x[px*33 + j];

    const int cls = ((gy & 1) << 1) | (gx & 1);
    const float* Mb = ws + WS_M + cls*992;
    const int i0 = sub ? 16 : 0, ni = sub ? 15 : 16;
    #pragma unroll 1
    for (int k = 0; k < ni; ++k) {
        const int i = i0 + k;
        float acc = fc[i*252];
        #pragma unroll
        for (int j = 0; j < 31; ++j) acc += Mb[i*32 + j] * o2f[j];
        out[i*65536 + gy*256 + gx] = acc;
    }
}

extern "C" void kernel_launch(void* const* d_in, const int* in_sizes, int n_in,
                              void* d_out, int out_size, void* d_ws, size_t ws_size,
                              hipStream_t stream)
{
    const float* x   = (const float*)d_in[0];
    const float* WE  = (const float*)d_in[2];
    const float* WC  = (const float*)d_in[3];
    const float* W2  = (const float*)d_in[4];
    const float* bw1 = (const float*)d_in[5];
    const float* bb1 = (const float*)d_in[6];
    const float* bw2 = (const float*)d_in[7];
    const float* bb2 = (const float*)d_in[8];
    const float* r2w = (const float*)d_in[9];
    const float* r2b = (const float*)d_in[10];
    const float* ow  = (const float*)d_in[11];
    const float* ob  = (const float*)d_in[12];
    const float* l1w = (const float*)d_in[13];
    const float* l1b = (const float*)d_in[14];
    const float* l2w = (const float*)d_in[15];
    const float* l2b = (const float*)d_in[16];
    float* ws  = (float*)d_ws;
    float* out = (float*)d_out;

    const size_t need = (size_t)(WS_FEA + 260*260*36) * 4;
    if (ws_size >= need) {
        hipLaunchKernelGGL(prepfill_kernel, dim3(281), dim3(256), 0, stream,
                           x, WE, WC, W2, bw1, bb1, bw2, bb2, r2w, r2b,
                           ow, ob, l1w, l1b, l2w, l2b, ws);
        hipLaunchKernelGGL(conv4_kernel, dim3(16, 32), dim3(256), 0, stream,
                           ws, out);
    } else {
        hipLaunchKernelGGL(prep_only_kernel, dim3(16), dim3(256), 0, stream,
                           WE, WC, W2, bw1, bb1, bw2, bb2, r2w, r2b,
                           ow, ob, l1w, l1b, l2w, l2b, ws);
        hipLaunchKernelGGL(conv_fb_kernel, dim3(16, 32), dim3(256), 0, stream,
                           x, ws, out);
    }
}